// Round 9
// baseline (74.815 us; speedup 1.0000x reference)
//
#include <hip/hip_runtime.h>
#include <hip/hip_fp16.h>

// Problem constants (from reference setup_inputs)
#define NH 4       // heads
#define NQ 64      // queries
#define NK 64      // index dim
#define NI 2048    // items
#define ND 128     // d_model
#define NHI (NH * NI)              // 8192 flat score columns per query
#define REC_ELEMS ((size_t)NQ * NHI * ND)  // 67108864 floats, output 0

typedef float f32x4 __attribute__((ext_vector_type(4)));

// ---------------------------------------------------------------------------
// Kernel A: score matmul, loop-inverted (each index row read once per 8 lanes).
// Grid: 256 blocks = (h, 32-item chunk) x 256 threads.
// Thread t: item = chunk*32 + (t&31); computes 8 queries q = (t>>5)*8 + 0..7.
// Query tile (fp16-rounded) staged in LDS, read back as float4 (ds_read_b128).
// Per score: the exact validated FP order — sequential f32 chain, mul+add
// separate (contract off), k-order consumption, final fp16 round. Bit-exact
// vs numpy HALF matmul (absmax 0.0, R2/R4-R8).
// ---------------------------------------------------------------------------
__global__ __launch_bounds__(256) void score_kernel(
    const float* __restrict__ query,   // (NH, NQ, NK)
    const float* __restrict__ index,   // (NI, NK)
    float* __restrict__ score_out) {   // (NQ, NHI)
#pragma clang fp contract(off)
  const int b      = blockIdx.x;
  const int h      = b >> 6;           // head
  const int ic     = b & 63;           // item chunk (32 items)
  const int t      = threadIdx.x;      // 0..255
  const int i      = ic * 32 + (t & 31);
  const int qbase  = (t >> 5) * 8;     // 8 queries per thread

  __shared__ f32x4 qs4[NQ * NK / 4];   // fp16-rounded query tile for head h
  {
    const float4* qg4 = (const float4*)(query + (size_t)h * NQ * NK);
#pragma unroll
    for (int c = 0; c < 4; ++c) {      // 1024 float4 / 256 threads
      float4 v = qg4[c * 256 + t];
      f32x4 w = {__half2float(__float2half(v.x)), __half2float(__float2half(v.y)),
                 __half2float(__float2half(v.z)), __half2float(__float2half(v.w))};
      qs4[c * 256 + t] = w;
    }
  }
  __syncthreads();

  // item row -> registers, fp16-rounded
  float r[NK];
  const float4* row4 = (const float4*)(index + (size_t)i * NK);
#pragma unroll
  for (int c = 0; c < 16; ++c) {
    float4 v = row4[c];
    r[c * 4 + 0] = __half2float(__float2half(v.x));
    r[c * 4 + 1] = __half2float(__float2half(v.y));
    r[c * 4 + 2] = __half2float(__float2half(v.z));
    r[c * 4 + 3] = __half2float(__float2half(v.w));
  }

#pragma unroll
  for (int qi = 0; qi < 8; ++qi) {     // 8 independent chains
    const int q = qbase + qi;
    const f32x4* qrow4 = qs4 + q * (NK / 4);
    float acc = 0.0f;
#pragma unroll
    for (int c = 0; c < 16; ++c) {     // float4 LDS read, k-order consumption
      f32x4 qv = qrow4[c];
      acc = acc + qv.x * r[c * 4 + 0]; // numpy HALF_dot order preserved
      acc = acc + qv.y * r[c * 4 + 1];
      acc = acc + qv.z * r[c * 4 + 2];
      acc = acc + qv.w * r[c * 4 + 3];
    }
    score_out[(size_t)q * NHI + h * NI + i] = __half2float(__float2half(acc));
  }
}

// ---------------------------------------------------------------------------
// Kernel B: per query row, stable compaction of passing flat indices.
// One block (512 threads = 8 waves) per q; each thread owns 16 consecutive
// columns (float4 loads). Scan = per-wave __shfl_up inclusive scan + single
// cross-wave LDS fix-up (1 barrier).
// ---------------------------------------------------------------------------
__global__ __launch_bounds__(512) void compact_kernel(
    const float* __restrict__ score,   // (NQ, NHI)
    int* __restrict__ comp,            // (NQ, NHI) compacted indices
    int* __restrict__ npass) {         // (NQ)
  const int q = blockIdx.x;
  const int t = threadIdx.x;
  const int lane = t & 63;
  const int w = t >> 6;                // wave id, 0..7
  const int base = t * 16;
  const float* srow = score + (size_t)q * NHI;

  float s[16];
  const float4* s4 = (const float4*)(srow + base);
#pragma unroll
  for (int j4 = 0; j4 < 4; ++j4) {
    float4 v = s4[j4];
    s[j4 * 4 + 0] = v.x; s[j4 * 4 + 1] = v.y;
    s[j4 * 4 + 2] = v.z; s[j4 * 4 + 3] = v.w;
  }

  int cnt = 0;
#pragma unroll
  for (int j = 0; j < 16; ++j) cnt += (s[j] > 0.1f) ? 1 : 0;

  // wave-level inclusive scan of cnt
  int v = cnt;
#pragma unroll
  for (int d = 1; d < 64; d <<= 1) {
    int u = __shfl_up(v, d);
    if (lane >= d) v += u;
  }

  __shared__ int wsum[8];
  if (lane == 63) wsum[w] = v;
  __syncthreads();

  int woff = 0;
#pragma unroll
  for (int k = 0; k < 8; ++k) woff += (k < w) ? wsum[k] : 0;

  int pos = woff + v - cnt;            // exclusive prefix over all 512 threads
  int* crow = comp + (size_t)q * NHI;
#pragma unroll
  for (int j = 0; j < 16; ++j) {
    if (s[j] > 0.1f) crow[pos++] = base + j;
  }
  if (t == 511) npass[q] = woff + v;   // grand total
}

// ---------------------------------------------------------------------------
// Kernel C: the big write. Each wave owns 64 CONSECUTIVE output rows (32 KB),
// all within one query q. pass_rows is WAVE-UNIFORM: branch-free pass pairs,
// one predicated boundary pair, then a pure-store zero loop.
// NONTEMPORAL stores on the 256 MiB output stream: no L2 allocation, so the
// 1 MiB record working set stays L2-resident for the gather reads and HBM
// sees a pure write stream (theory: R8's ~5 TB/s effective was store-thrash
// evicting record from L2).
// 2048 blocks x 256 threads = 8192 waves x 64 rows = 524288 rows exactly.
// ---------------------------------------------------------------------------
__global__ __launch_bounds__(256) void write_kernel(
    const float* __restrict__ score,   // (NQ, NHI)
    const float* __restrict__ record,  // (NI, ND)
    const int* __restrict__ comp,      // (NQ, NHI)
    const int* __restrict__ npass,     // (NQ)
    float* __restrict__ out) {         // (NQ, NHI, ND)
  const int lane = threadIdx.x & 63;
  const int half = lane >> 5;          // which row of the current pair
  const int l32  = lane & 31;          // float4 slot within the row
  const int wave = blockIdx.x * 4 + (threadIdx.x >> 6);  // 0..8191
  const size_t r0 = (size_t)wave << 6; // first of 64 rows in this chunk
  const int q  = (int)(r0 >> 13);
  const int p0 = (int)(r0 & (NHI - 1));

  int pass_rows = npass[q] - p0;       // rows in this chunk that are scaled
  pass_rows = pass_rows < 0 ? 0 : (pass_rows > 64 ? 64 : pass_rows);

  // Preload this chunk's comp/score, one row per lane (coalesced).
  int   j_lane = 0;
  float s_lane = 0.0f;
  if (lane < pass_rows) {
    j_lane = comp[r0 + lane];
    s_lane = score[((size_t)q << 13) + j_lane];
  }

  float* outbase = out + (r0 << 7);
  const int fp = pass_rows >> 1;       // full pass pairs (wave-uniform)

#pragma unroll 8
  for (int i = 0; i < fp; ++i) {       // branch-free: both rows pass
    const int ro = 2 * i + half;
    const int   j = __shfl(j_lane, ro);
    const float s = __shfl(s_lane, ro);
    const f32x4* rec = (const f32x4*)(record + ((size_t)(j & (NI - 1)) << 7));
    f32x4 val = s * rec[l32];
    __builtin_nontemporal_store(val, (f32x4*)(outbase + ((size_t)ro << 7)) + l32);
  }

  if (pass_rows & 1) {                 // boundary pair: row passes, row+1 zero
    const int ro = 2 * fp + half;
    const int   j = __shfl(j_lane, ro);
    const float s = __shfl(s_lane, ro);
    f32x4 val = {0.0f, 0.0f, 0.0f, 0.0f};
    if (half == 0) {
      const f32x4* rec = (const f32x4*)(record + ((size_t)(j & (NI - 1)) << 7));
      val = s * rec[l32];
    }
    __builtin_nontemporal_store(val, (f32x4*)(outbase + ((size_t)ro << 7)) + l32);
  }

  const int zstart = fp + (pass_rows & 1);
  const f32x4 z = {0.0f, 0.0f, 0.0f, 0.0f};
#pragma unroll 8
  for (int i = zstart; i < 32; ++i) {  // pure fill, no loads
    const int ro = 2 * i + half;
    __builtin_nontemporal_store(z, (f32x4*)(outbase + ((size_t)ro << 7)) + l32);
  }
}

// ---------------------------------------------------------------------------
extern "C" void kernel_launch(void* const* d_in, const int* in_sizes, int n_in,
                              void* d_out, int out_size, void* d_ws, size_t ws_size,
                              hipStream_t stream) {
  const float* query  = (const float*)d_in[0];  // (NH, NQ, NK)
  const float* record = (const float*)d_in[1];  // (NI, ND)
  const float* index  = (const float*)d_in[2];  // (NI, NK)

  float* out       = (float*)d_out;
  float* score_out = out + REC_ELEMS;           // output 1 region: (NQ, NHI)

  int* comp  = (int*)d_ws;                      // (NQ, NHI) ints = 2 MiB
  int* npass = comp + (size_t)NQ * NHI;         // (NQ) ints

  score_kernel<<<NH * 64, 256, 0, stream>>>(query, index, score_out);
  compact_kernel<<<NQ, 512, 0, stream>>>(score_out, comp, npass);
  write_kernel<<<2048, 256, 0, stream>>>(score_out, record, comp, npass, out);
}

// Round 10
// 64.315 us; speedup vs baseline: 1.1633x; 1.1633x over previous
//
#include <hip/hip_runtime.h>
#include <hip/hip_fp16.h>

// Problem constants (from reference setup_inputs)
#define NH 4       // heads
#define NQ 64      // queries
#define NK 64      // index dim
#define NI 2048    // items
#define ND 128     // d_model
#define NHI (NH * NI)              // 8192 flat score columns per query
#define REC_ELEMS ((size_t)NQ * NHI * ND)  // 67108864 floats, output 0

typedef float f32x4 __attribute__((ext_vector_type(4)));

// ---------------------------------------------------------------------------
// Kernel A: score matmul, loop-inverted (each index row read once per 8 lanes).
// Grid: 256 blocks = (h, 32-item chunk) x 256 threads.
// Thread t: item = chunk*32 + (t&31); computes 8 queries q = (t>>5)*8 + 0..7.
// Query tile (fp16-rounded) staged in LDS, read back as float4 (ds_read_b128).
// Per score: the exact validated FP order — sequential f32 chain, mul+add
// separate (contract off), k-order consumption, final fp16 round. Bit-exact
// vs numpy HALF matmul (absmax 0.0, R2/R4-R9).
// ---------------------------------------------------------------------------
__global__ __launch_bounds__(256) void score_kernel(
    const float* __restrict__ query,   // (NH, NQ, NK)
    const float* __restrict__ index,   // (NI, NK)
    float* __restrict__ score_out) {   // (NQ, NHI)
#pragma clang fp contract(off)
  const int b      = blockIdx.x;
  const int h      = b >> 6;           // head
  const int ic     = b & 63;           // item chunk (32 items)
  const int t      = threadIdx.x;      // 0..255
  const int i      = ic * 32 + (t & 31);
  const int qbase  = (t >> 5) * 8;     // 8 queries per thread

  __shared__ f32x4 qs4[NQ * NK / 4];   // fp16-rounded query tile for head h
  {
    const float4* qg4 = (const float4*)(query + (size_t)h * NQ * NK);
#pragma unroll
    for (int c = 0; c < 4; ++c) {      // 1024 float4 / 256 threads
      float4 v = qg4[c * 256 + t];
      f32x4 w = {__half2float(__float2half(v.x)), __half2float(__float2half(v.y)),
                 __half2float(__float2half(v.z)), __half2float(__float2half(v.w))};
      qs4[c * 256 + t] = w;
    }
  }
  __syncthreads();

  // item row -> registers, fp16-rounded
  float r[NK];
  const float4* row4 = (const float4*)(index + (size_t)i * NK);
#pragma unroll
  for (int c = 0; c < 16; ++c) {
    float4 v = row4[c];
    r[c * 4 + 0] = __half2float(__float2half(v.x));
    r[c * 4 + 1] = __half2float(__float2half(v.y));
    r[c * 4 + 2] = __half2float(__float2half(v.z));
    r[c * 4 + 3] = __half2float(__float2half(v.w));
  }

#pragma unroll
  for (int qi = 0; qi < 8; ++qi) {     // 8 independent chains
    const int q = qbase + qi;
    const f32x4* qrow4 = qs4 + q * (NK / 4);
    float acc = 0.0f;
#pragma unroll
    for (int c = 0; c < 16; ++c) {     // float4 LDS read, k-order consumption
      f32x4 qv = qrow4[c];
      acc = acc + qv.x * r[c * 4 + 0]; // numpy HALF_dot order preserved
      acc = acc + qv.y * r[c * 4 + 1];
      acc = acc + qv.z * r[c * 4 + 2];
      acc = acc + qv.w * r[c * 4 + 3];
    }
    score_out[(size_t)q * NHI + h * NI + i] = __half2float(__float2half(acc));
  }
}

// ---------------------------------------------------------------------------
// Kernel B: per query row, stable compaction of passing flat indices.
// One block (512 threads = 8 waves) per q; each thread owns 16 consecutive
// columns (float4 loads). Scan = per-wave __shfl_up inclusive scan + single
// cross-wave LDS fix-up (1 barrier).
// ---------------------------------------------------------------------------
__global__ __launch_bounds__(512) void compact_kernel(
    const float* __restrict__ score,   // (NQ, NHI)
    int* __restrict__ comp,            // (NQ, NHI) compacted indices
    int* __restrict__ npass) {         // (NQ)
  const int q = blockIdx.x;
  const int t = threadIdx.x;
  const int lane = t & 63;
  const int w = t >> 6;                // wave id, 0..7
  const int base = t * 16;
  const float* srow = score + (size_t)q * NHI;

  float s[16];
  const float4* s4 = (const float4*)(srow + base);
#pragma unroll
  for (int j4 = 0; j4 < 4; ++j4) {
    float4 v = s4[j4];
    s[j4 * 4 + 0] = v.x; s[j4 * 4 + 1] = v.y;
    s[j4 * 4 + 2] = v.z; s[j4 * 4 + 3] = v.w;
  }

  int cnt = 0;
#pragma unroll
  for (int j = 0; j < 16; ++j) cnt += (s[j] > 0.1f) ? 1 : 0;

  // wave-level inclusive scan of cnt
  int v = cnt;
#pragma unroll
  for (int d = 1; d < 64; d <<= 1) {
    int u = __shfl_up(v, d);
    if (lane >= d) v += u;
  }

  __shared__ int wsum[8];
  if (lane == 63) wsum[w] = v;
  __syncthreads();

  int woff = 0;
#pragma unroll
  for (int k = 0; k < 8; ++k) woff += (k < w) ? wsum[k] : 0;

  int pos = woff + v - cnt;            // exclusive prefix over all 512 threads
  int* crow = comp + (size_t)q * NHI;
#pragma unroll
  for (int j = 0; j < 16; ++j) {
    if (s[j] > 0.1f) crow[pos++] = base + j;
  }
  if (t == 511) npass[q] = woff + v;   // grand total
}

// ---------------------------------------------------------------------------
// Kernel C: the big write. Each wave owns 64 CONSECUTIVE output rows (32 KB),
// all within one query q. pass_rows is WAVE-UNIFORM: branch-free pass pairs
// (unroll 16 for deep load pipelining), one predicated boundary pair, then a
// pure-store zero loop. PLAIN stores (NT measured +12 us in R9 — never again).
// comp/score preloaded one-per-lane, distributed via __shfl.
// 2048 blocks x 256 threads = 8192 waves x 64 rows = 524288 rows exactly.
// ---------------------------------------------------------------------------
__global__ __launch_bounds__(256) void write_kernel(
    const float* __restrict__ score,   // (NQ, NHI)
    const float* __restrict__ record,  // (NI, ND)
    const int* __restrict__ comp,      // (NQ, NHI)
    const int* __restrict__ npass,     // (NQ)
    float* __restrict__ out) {         // (NQ, NHI, ND)
  const int lane = threadIdx.x & 63;
  const int half = lane >> 5;          // which row of the current pair
  const int l32  = lane & 31;          // float4 slot within the row
  const int wave = blockIdx.x * 4 + (threadIdx.x >> 6);  // 0..8191
  const size_t r0 = (size_t)wave << 6; // first of 64 rows in this chunk
  const int q  = (int)(r0 >> 13);
  const int p0 = (int)(r0 & (NHI - 1));

  int pass_rows = npass[q] - p0;       // rows in this chunk that are scaled
  pass_rows = pass_rows < 0 ? 0 : (pass_rows > 64 ? 64 : pass_rows);

  // Preload this chunk's comp/score, one row per lane (coalesced).
  int   j_lane = 0;
  float s_lane = 0.0f;
  if (lane < pass_rows) {
    j_lane = comp[r0 + lane];
    s_lane = score[((size_t)q << 13) + j_lane];
  }

  float* outbase = out + (r0 << 7);
  const int fp = pass_rows >> 1;       // full pass pairs (wave-uniform)

#pragma unroll 16
  for (int i = 0; i < fp; ++i) {       // branch-free: both rows pass
    const int ro = 2 * i + half;
    const int   j = __shfl(j_lane, ro);
    const float s = __shfl(s_lane, ro);
    const f32x4* rec = (const f32x4*)(record + ((size_t)(j & (NI - 1)) << 7));
    f32x4 val = s * rec[l32];
    *((f32x4*)(outbase + ((size_t)ro << 7)) + l32) = val;
  }

  if (pass_rows & 1) {                 // boundary pair: row passes, row+1 zero
    const int ro = 2 * fp + half;
    const int   j = __shfl(j_lane, ro);
    const float s = __shfl(s_lane, ro);
    f32x4 val = {0.0f, 0.0f, 0.0f, 0.0f};
    if (half == 0) {
      const f32x4* rec = (const f32x4*)(record + ((size_t)(j & (NI - 1)) << 7));
      val = s * rec[l32];
    }
    *((f32x4*)(outbase + ((size_t)ro << 7)) + l32) = val;
  }

  const int zstart = fp + (pass_rows & 1);
  const f32x4 z = {0.0f, 0.0f, 0.0f, 0.0f};
#pragma unroll 8
  for (int i = zstart; i < 32; ++i) {  // pure fill, no loads
    const int ro = 2 * i + half;
    *((f32x4*)(outbase + ((size_t)ro << 7)) + l32) = z;
  }
}

// ---------------------------------------------------------------------------
extern "C" void kernel_launch(void* const* d_in, const int* in_sizes, int n_in,
                              void* d_out, int out_size, void* d_ws, size_t ws_size,
                              hipStream_t stream) {
  const float* query  = (const float*)d_in[0];  // (NH, NQ, NK)
  const float* record = (const float*)d_in[1];  // (NI, ND)
  const float* index  = (const float*)d_in[2];  // (NI, NK)

  float* out       = (float*)d_out;
  float* score_out = out + REC_ELEMS;           // output 1 region: (NQ, NHI)

  int* comp  = (int*)d_ws;                      // (NQ, NHI) ints = 2 MiB
  int* npass = comp + (size_t)NQ * NHI;         // (NQ) ints

  score_kernel<<<NH * 64, 256, 0, stream>>>(query, index, score_out);
  compact_kernel<<<NQ, 512, 0, stream>>>(score_out, comp, npass);
  write_kernel<<<2048, 256, 0, stream>>>(score_out, record, comp, npass, out);
}

// Round 11
// 58.241 us; speedup vs baseline: 1.2846x; 1.1043x over previous
//
#include <hip/hip_runtime.h>
#include <hip/hip_fp16.h>

// Problem constants (from reference setup_inputs)
#define NH 4       // heads
#define NQ 64      // queries
#define NK 64      // index dim
#define NI 2048    // items
#define ND 128     // d_model
#define NHI (NH * NI)              // 8192 flat score columns per query
#define REC_ELEMS ((size_t)NQ * NHI * ND)  // 67108864 floats, output 0

typedef float f32x4 __attribute__((ext_vector_type(4)));

// ---------------------------------------------------------------------------
// Kernel A: score matmul, loop-inverted (each index row read once per 8 lanes).
// Grid: 256 blocks = (h, 32-item chunk) x 256 threads.
// Thread t: item = chunk*32 + (t&31); computes 8 queries q = (t>>5)*8 + 0..7.
// Query tile (fp16-rounded) staged in LDS, read back as float4 (ds_read_b128).
// Per score: the exact validated FP order — sequential f32 chain, mul+add
// separate (contract off), k-order consumption, final fp16 round. Bit-exact
// vs numpy HALF matmul (absmax 0.0, R2/R4-R10).
// ---------------------------------------------------------------------------
__global__ __launch_bounds__(256) void score_kernel(
    const float* __restrict__ query,   // (NH, NQ, NK)
    const float* __restrict__ index,   // (NI, NK)
    float* __restrict__ score_out) {   // (NQ, NHI)
#pragma clang fp contract(off)
  const int b      = blockIdx.x;
  const int h      = b >> 6;           // head
  const int ic     = b & 63;           // item chunk (32 items)
  const int t      = threadIdx.x;      // 0..255
  const int i      = ic * 32 + (t & 31);
  const int qbase  = (t >> 5) * 8;     // 8 queries per thread

  __shared__ f32x4 qs4[NQ * NK / 4];   // fp16-rounded query tile for head h
  {
    const float4* qg4 = (const float4*)(query + (size_t)h * NQ * NK);
#pragma unroll
    for (int c = 0; c < 4; ++c) {      // 1024 float4 / 256 threads
      float4 v = qg4[c * 256 + t];
      f32x4 w = {__half2float(__float2half(v.x)), __half2float(__float2half(v.y)),
                 __half2float(__float2half(v.z)), __half2float(__float2half(v.w))};
      qs4[c * 256 + t] = w;
    }
  }
  __syncthreads();

  // item row -> registers, fp16-rounded
  float r[NK];
  const float4* row4 = (const float4*)(index + (size_t)i * NK);
#pragma unroll
  for (int c = 0; c < 16; ++c) {
    float4 v = row4[c];
    r[c * 4 + 0] = __half2float(__float2half(v.x));
    r[c * 4 + 1] = __half2float(__float2half(v.y));
    r[c * 4 + 2] = __half2float(__float2half(v.z));
    r[c * 4 + 3] = __half2float(__float2half(v.w));
  }

#pragma unroll
  for (int qi = 0; qi < 8; ++qi) {     // 8 independent chains
    const int q = qbase + qi;
    const f32x4* qrow4 = qs4 + q * (NK / 4);
    float acc = 0.0f;
#pragma unroll
    for (int c = 0; c < 16; ++c) {     // float4 LDS read, k-order consumption
      f32x4 qv = qrow4[c];
      acc = acc + qv.x * r[c * 4 + 0]; // numpy HALF_dot order preserved
      acc = acc + qv.y * r[c * 4 + 1];
      acc = acc + qv.z * r[c * 4 + 2];
      acc = acc + qv.w * r[c * 4 + 3];
    }
    score_out[(size_t)q * NHI + h * NI + i] = __half2float(__float2half(acc));
  }
}

// ---------------------------------------------------------------------------
// Kernel B: per query row, stable compaction of passing flat indices.
// One block (512 threads = 8 waves) per q; each thread owns 16 consecutive
// columns (float4 loads). Scan = per-wave __shfl_up inclusive scan + single
// cross-wave LDS fix-up (1 barrier).
// ---------------------------------------------------------------------------
__global__ __launch_bounds__(512) void compact_kernel(
    const float* __restrict__ score,   // (NQ, NHI)
    int* __restrict__ comp,            // (NQ, NHI) compacted indices
    int* __restrict__ npass) {         // (NQ)
  const int q = blockIdx.x;
  const int t = threadIdx.x;
  const int lane = t & 63;
  const int w = t >> 6;                // wave id, 0..7
  const int base = t * 16;
  const float* srow = score + (size_t)q * NHI;

  float s[16];
  const float4* s4 = (const float4*)(srow + base);
#pragma unroll
  for (int j4 = 0; j4 < 4; ++j4) {
    float4 v = s4[j4];
    s[j4 * 4 + 0] = v.x; s[j4 * 4 + 1] = v.y;
    s[j4 * 4 + 2] = v.z; s[j4 * 4 + 3] = v.w;
  }

  int cnt = 0;
#pragma unroll
  for (int j = 0; j < 16; ++j) cnt += (s[j] > 0.1f) ? 1 : 0;

  // wave-level inclusive scan of cnt
  int v = cnt;
#pragma unroll
  for (int d = 1; d < 64; d <<= 1) {
    int u = __shfl_up(v, d);
    if (lane >= d) v += u;
  }

  __shared__ int wsum[8];
  if (lane == 63) wsum[w] = v;
  __syncthreads();

  int woff = 0;
#pragma unroll
  for (int k = 0; k < 8; ++k) woff += (k < w) ? wsum[k] : 0;

  int pos = woff + v - cnt;            // exclusive prefix over all 512 threads
  int* crow = comp + (size_t)q * NHI;
#pragma unroll
  for (int j = 0; j < 16; ++j) {
    if (s[j] > 0.1f) crow[pos++] = base + j;
  }
  if (t == 511) npass[q] = woff + v;   // grand total
}

// ---------------------------------------------------------------------------
// Kernel C: the big write. Each wave owns 32 CONSECUTIVE output rows (16 KB),
// all within one query q (chunk halved vs R8 to reduce end-of-kernel tail
// imbalance between all-pass waves and all-zero waves). pass_rows is
// WAVE-UNIFORM: branch-free pass pairs (unroll 8), one predicated boundary
// pair, then a pure-store zero loop. PLAIN stores (NT measured +12us in R9).
// comp/score preloaded one-per-lane (lanes 0-31), distributed via __shfl.
// 4096 blocks x 256 threads = 16384 waves x 32 rows = 524288 rows exactly.
// ---------------------------------------------------------------------------
__global__ __launch_bounds__(256) void write_kernel(
    const float* __restrict__ score,   // (NQ, NHI)
    const float* __restrict__ record,  // (NI, ND)
    const int* __restrict__ comp,      // (NQ, NHI)
    const int* __restrict__ npass,     // (NQ)
    float* __restrict__ out) {         // (NQ, NHI, ND)
  const int lane = threadIdx.x & 63;
  const int half = lane >> 5;          // which row of the current pair
  const int l32  = lane & 31;          // float4 slot within the row
  const int wave = blockIdx.x * 4 + (threadIdx.x >> 6);  // 0..16383
  const size_t r0 = (size_t)wave << 5; // first of 32 rows in this chunk
  const int q  = (int)(r0 >> 13);
  const int p0 = (int)(r0 & (NHI - 1));

  int pass_rows = npass[q] - p0;       // rows in this chunk that are scaled
  pass_rows = pass_rows < 0 ? 0 : (pass_rows > 32 ? 32 : pass_rows);

  // Preload this chunk's comp/score, one row per lane (lanes 0-31, coalesced).
  int   j_lane = 0;
  float s_lane = 0.0f;
  if (lane < pass_rows) {
    j_lane = comp[r0 + lane];
    s_lane = score[((size_t)q << 13) + j_lane];
  }

  float* outbase = out + (r0 << 7);
  const int fp = pass_rows >> 1;       // full pass pairs (wave-uniform)

#pragma unroll 8
  for (int i = 0; i < fp; ++i) {       // branch-free: both rows pass
    const int ro = 2 * i + half;
    const int   j = __shfl(j_lane, ro);
    const float s = __shfl(s_lane, ro);
    const f32x4* rec = (const f32x4*)(record + ((size_t)(j & (NI - 1)) << 7));
    f32x4 val = s * rec[l32];
    *((f32x4*)(outbase + ((size_t)ro << 7)) + l32) = val;
  }

  if (pass_rows & 1) {                 // boundary pair: row passes, row+1 zero
    const int ro = 2 * fp + half;
    const int   j = __shfl(j_lane, ro);
    const float s = __shfl(s_lane, ro);
    f32x4 val = {0.0f, 0.0f, 0.0f, 0.0f};
    if (half == 0) {
      const f32x4* rec = (const f32x4*)(record + ((size_t)(j & (NI - 1)) << 7));
      val = s * rec[l32];
    }
    *((f32x4*)(outbase + ((size_t)ro << 7)) + l32) = val;
  }

  const int zstart = fp + (pass_rows & 1);
  const f32x4 z = {0.0f, 0.0f, 0.0f, 0.0f};
#pragma unroll 8
  for (int i = zstart; i < 16; ++i) {  // pure fill, no loads
    const int ro = 2 * i + half;
    *((f32x4*)(outbase + ((size_t)ro << 7)) + l32) = z;
  }
}

// ---------------------------------------------------------------------------
extern "C" void kernel_launch(void* const* d_in, const int* in_sizes, int n_in,
                              void* d_out, int out_size, void* d_ws, size_t ws_size,
                              hipStream_t stream) {
  const float* query  = (const float*)d_in[0];  // (NH, NQ, NK)
  const float* record = (const float*)d_in[1];  // (NI, ND)
  const float* index  = (const float*)d_in[2];  // (NI, NK)

  float* out       = (float*)d_out;
  float* score_out = out + REC_ELEMS;           // output 1 region: (NQ, NHI)

  int* comp  = (int*)d_ws;                      // (NQ, NHI) ints = 2 MiB
  int* npass = comp + (size_t)NQ * NHI;         // (NQ) ints

  score_kernel<<<NH * 64, 256, 0, stream>>>(query, index, score_out);
  compact_kernel<<<NQ, 512, 0, stream>>>(score_out, comp, npass);
  write_kernel<<<4096, 256, 0, stream>>>(score_out, record, comp, npass, out);
}